// Round 5
// baseline (230.985 us; speedup 1.0000x reference)
//
#include <hip/hip_runtime.h>

// DHSMoEDetector: N=16384 tokens, D=768, H=768, C=2, E=20
#define N_D 768
#define N_H 768
#define N_C 2
#define N_E 20
#define MT 128
#define NT 128
#define BK 32
#define KT (N_D / BK)
#define MAX_TILES 160
#define ROWB (N_D * 2)  // row stride in bytes (bf16)

typedef __attribute__((ext_vector_type(8))) short short8;
typedef __attribute__((ext_vector_type(4))) float f32x4;

__device__ __forceinline__ unsigned short f2bf(float f) {
  unsigned u = __builtin_bit_cast(unsigned, f);
  u += 0x7FFFu + ((u >> 16) & 1u);
  return (unsigned short)(u >> 16);
}

#define GLD_LDS16(gp, lp)                                                        \
  __builtin_amdgcn_global_load_lds(                                              \
      (const __attribute__((address_space(1))) void*)(gp),                       \
      (__attribute__((address_space(3))) void*)(lp), 16, 0, 0)

// ---------------- sort-by-expert ----------------

__global__ __launch_bounds__(256) void k_hist(const int* __restrict__ cidx,
                                              int* __restrict__ counts, int n) {
  __shared__ int lc[N_E];
  if (threadIdx.x < N_E) lc[threadIdx.x] = 0;
  __syncthreads();
  for (int i = blockIdx.x * blockDim.x + threadIdx.x; i < n;
       i += gridDim.x * blockDim.x) {
    int e = cidx[i];
    e = e < 0 ? 0 : (e >= N_E ? N_E - 1 : e);
    atomicAdd(&lc[e], 1);
  }
  __syncthreads();
  if (threadIdx.x < N_E) atomicAdd(&counts[threadIdx.x], lc[threadIdx.x]);
}

// parallel scan + tile table (20 experts; each thread prefixes over <=20 ints)
__global__ __launch_bounds__(64) void k_scan(const int* __restrict__ counts,
                                             int* __restrict__ offsets,
                                             int* __restrict__ cursor,
                                             int* __restrict__ tiles,
                                             int* __restrict__ numTiles) {
  int t = threadIdx.x;
  if (t < N_E) {
    int run = 0, trun = 0;
    for (int e = 0; e < t; ++e) {
      run += counts[e];
      trun += (counts[e] + MT - 1) / MT;
    }
    offsets[t] = run;
    cursor[t] = run;
    int nt = (counts[t] + MT - 1) / MT;
    for (int m = 0; m < nt; ++m) tiles[trun + m] = (t << 8) | m;
    if (t == N_E - 1) *numTiles = trun + nt;
  }
}

__global__ __launch_bounds__(256) void k_scatter(const int* __restrict__ cidx,
                                                 int* __restrict__ cursor,
                                                 int* __restrict__ sorted, int n) {
  __shared__ int lc[N_E];
  __shared__ int lbase[N_E];
  int tid = threadIdx.x;
  if (tid < N_E) lc[tid] = 0;
  __syncthreads();
  int i = blockIdx.x * blockDim.x + tid;
  int e = 0, p = 0;
  if (i < n) {
    e = cidx[i];
    e = e < 0 ? 0 : (e >= N_E ? N_E - 1 : e);
    p = atomicAdd(&lc[e], 1);
  }
  __syncthreads();
  if (tid < N_E) lbase[tid] = atomicAdd(&cursor[tid], lc[tid]);
  __syncthreads();
  if (i < n) sorted[lbase[e] + p] = i;
}

// ---------------- gather embeddings into sorted order, fp32 -> bf16 --------

__global__ __launch_bounds__(192) void k_gather(const float* __restrict__ emb,
                                                const int* __restrict__ sorted,
                                                unsigned short* __restrict__ Xg,
                                                int n) {
  int row = blockIdx.x;
  int j = threadIdx.x;
  ushort4 o;
  if (row < n) {
    float4 v = ((const float4*)(emb + (size_t)sorted[row] * N_D))[j];
    o.x = f2bf(v.x);
    o.y = f2bf(v.y);
    o.z = f2bf(v.z);
    o.w = f2bf(v.w);
  } else {
    o.x = o.y = o.z = o.w = 0;
  }
  ((ushort4*)(Xg + (size_t)row * N_D))[j] = o;
}

// ---------------- W1 (E,D,H) fp32 -> W1t (E,H,D) bf16, 16B stores ----------

__global__ __launch_bounds__(256) void k_w1_cvt(const float* __restrict__ W1,
                                                unsigned short* __restrict__ W1t) {
  __shared__ float tile[64][65];
  int e = blockIdx.z, h0 = blockIdx.x * 64, d0 = blockIdx.y * 64;
  const float* src = W1 + (size_t)e * N_D * N_H;
  unsigned short* dst = W1t + (size_t)e * N_H * N_D;
  int tx = threadIdx.x & 15, ty = threadIdx.x >> 4;
  for (int s = 0; s < 4; ++s) {
    int d = s * 16 + ty;
    float4 v = *(const float4*)&src[(size_t)(d0 + d) * N_H + h0 + tx * 4];
    tile[d][tx * 4 + 0] = v.x;
    tile[d][tx * 4 + 1] = v.y;
    tile[d][tx * 4 + 2] = v.z;
    tile[d][tx * 4 + 3] = v.w;
  }
  __syncthreads();
  int px = threadIdx.x & 7, py = threadIdx.x >> 3;
  for (int s = 0; s < 2; ++s) {
    int h = s * 32 + py;
    short8 v;
    for (int j = 0; j < 8; ++j)
      v[j] = (short)f2bf(tile[px * 8 + j][h]);
    *(short8*)&dst[(size_t)(h0 + h) * N_D + d0 + px * 8] = v;
  }
}

// ---------------- fused grouped GEMM1 + relu + layer2 ----------------------
// Depth-3 software pipeline, triple-buffered LDS (48KB -> 3 blocks/CU), raw
// asm waitcnt+barrier (vmcnt never drains to 0 mid-loop; tail peeled with
// vmcnt 4/0). Chunk-major LDS -> conflict-free ds_read_b128.
// 1-D grid with XCD-affinity decode: all 6 n-blocks of an m-tile share
// p%8 (same XCD under round-robin dispatch) -> A-tile fetched beyond-L2 once.

__global__ __launch_bounds__(256, 3) void k_gemm(
    const unsigned short* __restrict__ Xg, const unsigned short* __restrict__ W1t,
    const float* __restrict__ b1, const float* __restrict__ W2,
    const float* __restrict__ b2, const int* __restrict__ sorted,
    const int* __restrict__ counts, const int* __restrict__ offsets,
    const int* __restrict__ tiles, const int* __restrict__ numTiles,
    float* __restrict__ out) {
  // decode: p = xcd + 8*(bx + 6*mth), mt = xcd + 8*mth
  const int p = blockIdx.x;
  const int xcd = p & 7;
  const int t = p >> 3;
  const int bx = t % 6;
  const int mth = t / 6;
  const int mt = xcd + 8 * mth;
  if (mt >= *numTiles) return;
  const int tv = tiles[mt];
  const int e = tv >> 8;
  const int m0 = (tv & 255) * MT;
  const int off = offsets[e];
  const int cnt_rel = counts[e] - m0;
  const int n0 = bx * NT;

  __shared__ unsigned short lA[3][MT * BK];  // 3 x 8KB, chunk-major groups
  __shared__ unsigned short lB[3][NT * BK];

  const int tid = threadIdx.x;
  const int wid = tid >> 6, lane = tid & 63;
  const int wm = (wid >> 1) * 64, wn = (wid & 1) * 64;
  const int quad = lane >> 4, lm = lane & 15;

  // staging lane mapping: row = lane&15 (+R0), k-chunk = lane>>4.
  const int R0 = wid * 32 + lm;
  const char* agp = (const char*)Xg + (size_t)(off + m0 + R0) * ROWB + quad * 16;
  const char* bgp = (const char*)W1t + (size_t)e * N_H * ROWB +
                    (size_t)(n0 + R0) * ROWB + quad * 16;
  unsigned short* lap[3] = {&lA[0][(wid * 32) * BK], &lA[1][(wid * 32) * BK],
                            &lA[2][(wid * 32) * BK]};
  unsigned short* lbp[3] = {&lB[0][(wid * 32) * BK], &lB[1][(wid * 32) * BK],
                            &lB[2][(wid * 32) * BK]};

#define ISSUE_BATCH(kk, b)                                                       \
  do {                                                                           \
    const char* a_ = agp + (kk)*64;                                              \
    const char* b_ = bgp + (kk)*64;                                              \
    GLD_LDS16(a_, lap[b]);                                                       \
    GLD_LDS16(a_ + 16 * ROWB, lap[b] + 16 * BK);                                 \
    GLD_LDS16(b_, lbp[b]);                                                       \
    GLD_LDS16(b_ + 16 * ROWB, lbp[b] + 16 * BK);                                 \
  } while (0)

  f32x4 acc[4][4] = {};

  ISSUE_BATCH(0, 0);
  ISSUE_BATCH(1, 1);
  ISSUE_BATCH(2, 2);

  // fragment address (chunk-major): elem = ((m>>4)*4 + quad)*128 + lm*8
  const int fa = quad * 128 + lm * 8;

#define GEMM_BODY(kt, cur, DO_ISSUE)                                             \
  do {                                                                           \
    short8 af[4], bfr[4];                                                        \
    for (int i = 0; i < 4; ++i)                                                  \
      af[i] = *(const short8*)&lA[cur][((wm >> 4) + i) * 512 + fa];              \
    for (int j = 0; j < 4; ++j)                                                  \
      bfr[j] = *(const short8*)&lB[cur][((wn >> 4) + j) * 512 + fa];             \
    asm volatile("s_waitcnt lgkmcnt(0)\n\ts_barrier" ::: "memory");              \
    if (DO_ISSUE) ISSUE_BATCH((kt) + 3, cur);                                    \
    for (int i = 0; i < 4; ++i)                                                  \
      for (int j = 0; j < 4; ++j)                                                \
        acc[i][j] = __builtin_amdgcn_mfma_f32_16x16x32_bf16(af[i], bfr[j],       \
                                                            acc[i][j], 0, 0, 0); \
  } while (0)

#pragma unroll
  for (int kt = 0; kt < KT - 2; ++kt) {
    const int cur = kt % 3;
    asm volatile("s_waitcnt vmcnt(8)\n\ts_barrier" ::: "memory");
    GEMM_BODY(kt, cur, kt < KT - 3);
  }
  {
    asm volatile("s_waitcnt vmcnt(4)\n\ts_barrier" ::: "memory");
    GEMM_BODY(KT - 2, (KT - 2) % 3, false);
  }
  {
    asm volatile("s_waitcnt vmcnt(0)\n\ts_barrier" ::: "memory");
    GEMM_BODY(KT - 1, (KT - 1) % 3, false);
  }

  // ---- fused epilogue: h = relu(acc + b1), y-partial = h * W2[e] ----
  // C/D layout: col = lane&15 (lm), row = quad*4 + reg
  float y0[4][4], y1[4][4];
  for (int i = 0; i < 4; ++i)
    for (int r = 0; r < 4; ++r) y0[i][r] = y1[i][r] = 0.f;

  for (int j = 0; j < 4; ++j) {
    int col = n0 + wn + j * 16 + lm;
    float bias = b1[e * N_H + col];
    float2 w2 = *(const float2*)&W2[((size_t)e * N_H + col) * N_C];
    for (int i = 0; i < 4; ++i) {
      f32x4 a = acc[i][j];
      for (int r = 0; r < 4; ++r) {
        float h = a[r] + bias;
        h = h > 0.f ? h : 0.f;
        y0[i][r] += h * w2.x;
        y1[i][r] += h * w2.y;
      }
    }
  }
  for (int s = 1; s < 16; s <<= 1) {
    for (int i = 0; i < 4; ++i)
      for (int r = 0; r < 4; ++r) {
        y0[i][r] += __shfl_xor(y0[i][r], s, 64);
        y1[i][r] += __shfl_xor(y1[i][r], s, 64);
      }
  }
  if (lm == 0) {
    const bool add_bias = (n0 == 0) && (wn == 0);
    float bb0 = add_bias ? b2[e * N_C + 0] : 0.f;
    float bb1 = add_bias ? b2[e * N_C + 1] : 0.f;
    for (int i = 0; i < 4; ++i) {
      for (int r = 0; r < 4; ++r) {
        int mrel = wm + i * 16 + quad * 4 + r;
        if (mrel < cnt_rel) {
          int token = sorted[off + m0 + mrel];
          atomicAdd(&out[(size_t)token * N_C + 0], y0[i][r] + bb0);
          atomicAdd(&out[(size_t)token * N_C + 1], y1[i][r] + bb1);
        }
      }
    }
  }
}

// ---------------- launch ----------------

extern "C" void kernel_launch(void* const* d_in, const int* in_sizes, int n_in,
                              void* d_out, int out_size, void* d_ws, size_t ws_size,
                              hipStream_t stream) {
  const float* emb = (const float*)d_in[0];
  const int* cidx = (const int*)d_in[1];
  const float* W1 = (const float*)d_in[2];
  const float* b1 = (const float*)d_in[3];
  const float* W2 = (const float*)d_in[4];
  const float* b2 = (const float*)d_in[5];
  float* out = (float*)d_out;
  const int n = in_sizes[1];

  char* ws = (char*)d_ws;
  int* counts = (int*)ws;
  int* offsets = (int*)(ws + 128);
  int* cursor = (int*)(ws + 256);
  int* numTiles = (int*)(ws + 384);
  int* tiles = (int*)(ws + 512);
  int* sorted = (int*)(ws + 2048);
  size_t sorted_bytes = ((size_t)n * 4 + 255) & ~(size_t)255;
  unsigned short* Xg = (unsigned short*)(ws + 2048 + sorted_bytes);
  int pcap = n + MT;  // zero-padded tail rows
  unsigned short* W1t = Xg + (size_t)pcap * N_D;

  hipMemsetAsync(d_ws, 0, 2048, stream);
  hipMemsetAsync(d_out, 0, (size_t)out_size * sizeof(float), stream);
  int nb = (n + 255) / 256;
  k_hist<<<nb, 256, 0, stream>>>(cidx, counts, n);
  k_scan<<<1, 64, 0, stream>>>(counts, offsets, cursor, tiles, numTiles);
  k_scatter<<<nb, 256, 0, stream>>>(cidx, cursor, sorted, n);
  k_gather<<<pcap, 192, 0, stream>>>(emb, sorted, Xg, n);
  k_w1_cvt<<<dim3(N_H / 64, N_D / 64, N_E), 256, 0, stream>>>(W1, W1t);
  k_gemm<<<8 * 6 * (MAX_TILES / 8), 256, 0, stream>>>(
      Xg, W1t, b1, W2, b2, sorted, counts, offsets, tiles, numTiles, out);
}

// Round 6
// 224.646 us; speedup vs baseline: 1.0282x; 1.0282x over previous
//
#include <hip/hip_runtime.h>

// DHSMoEDetector: N=16384 tokens, D=768, H=768, C=2, E=20
#define N_D 768
#define N_H 768
#define N_C 2
#define N_E 20
#define MT 128
#define NT 128
#define BK 32
#define KT (N_D / BK)
#define ROWB (N_D * 2)   // row stride in bytes (bf16)
#define SLOTMAX 160      // per-XCD slot capacity (3 experts * 8 tiles * 6 bx max)

typedef __attribute__((ext_vector_type(8))) short short8;
typedef __attribute__((ext_vector_type(4))) float f32x4;

__device__ __forceinline__ unsigned short f2bf(float f) {
  unsigned u = __builtin_bit_cast(unsigned, f);
  u += 0x7FFFu + ((u >> 16) & 1u);
  return (unsigned short)(u >> 16);
}

#define GLD_LDS16(gp, lp)                                                        \
  __builtin_amdgcn_global_load_lds(                                              \
      (const __attribute__((address_space(1))) void*)(gp),                       \
      (__attribute__((address_space(3))) void*)(lp), 16, 0, 0)

// ---------------- sort-by-expert ----------------

__global__ __launch_bounds__(256) void k_hist(const int* __restrict__ cidx,
                                              int* __restrict__ counts, int n) {
  __shared__ int lc[N_E];
  if (threadIdx.x < N_E) lc[threadIdx.x] = 0;
  __syncthreads();
  for (int i = blockIdx.x * blockDim.x + threadIdx.x; i < n;
       i += gridDim.x * blockDim.x) {
    int e = cidx[i];
    e = e < 0 ? 0 : (e >= N_E ? N_E - 1 : e);
    atomicAdd(&lc[e], 1);
  }
  __syncthreads();
  if (threadIdx.x < N_E) atomicAdd(&counts[threadIdx.x], lc[threadIdx.x]);
}

// scan + per-XCD slot table. XCD x owns experts x, x+8, x+16: for each expert,
// m-tiles outer, the 6 n-blocks inner-consecutive (B slice stays hot in that
// XCD's L2; A-tile reused 6x back-to-back).
__global__ __launch_bounds__(64) void k_scan(const int* __restrict__ counts,
                                             int* __restrict__ offsets,
                                             int* __restrict__ cursor,
                                             int* __restrict__ slots) {
  int t = threadIdx.x;
  if (t < N_E) {
    int run = 0;
    for (int e = 0; e < t; ++e) run += counts[e];
    offsets[t] = run;
    cursor[t] = run;
  }
  if (t < 8) {
    int idx = 0;
    for (int e = t; e < N_E; e += 8) {
      int nt = (counts[e] + MT - 1) / MT;
      for (int m = 0; m < nt; ++m)
        for (int bx = 0; bx < 6; ++bx)
          if (idx < SLOTMAX) slots[t * SLOTMAX + idx++] = e | (m << 8) | (bx << 16);
    }
    for (; idx < SLOTMAX; ++idx) slots[t * SLOTMAX + idx] = -1;
  }
}

__global__ __launch_bounds__(256) void k_scatter(const int* __restrict__ cidx,
                                                 int* __restrict__ cursor,
                                                 int* __restrict__ sorted, int n) {
  __shared__ int lc[N_E];
  __shared__ int lbase[N_E];
  int tid = threadIdx.x;
  if (tid < N_E) lc[tid] = 0;
  __syncthreads();
  int i = blockIdx.x * blockDim.x + tid;
  int e = 0, p = 0;
  if (i < n) {
    e = cidx[i];
    e = e < 0 ? 0 : (e >= N_E ? N_E - 1 : e);
    p = atomicAdd(&lc[e], 1);
  }
  __syncthreads();
  if (tid < N_E) lbase[tid] = atomicAdd(&cursor[tid], lc[tid]);
  __syncthreads();
  if (i < n) sorted[lbase[e] + p] = i;
}

// ---------------- gather embeddings into sorted order, fp32 -> bf16 --------

__global__ __launch_bounds__(192) void k_gather(const float* __restrict__ emb,
                                                const int* __restrict__ sorted,
                                                unsigned short* __restrict__ Xg,
                                                int n) {
  int row = blockIdx.x;
  int j = threadIdx.x;
  ushort4 o;
  if (row < n) {
    float4 v = ((const float4*)(emb + (size_t)sorted[row] * N_D))[j];
    o.x = f2bf(v.x);
    o.y = f2bf(v.y);
    o.z = f2bf(v.z);
    o.w = f2bf(v.w);
  } else {
    o.x = o.y = o.z = o.w = 0;
  }
  ((ushort4*)(Xg + (size_t)row * N_D))[j] = o;
}

// ---------------- W1 (E,D,H) fp32 -> W1t (E,H,D) bf16, 16B stores ----------

__global__ __launch_bounds__(256) void k_w1_cvt(const float* __restrict__ W1,
                                                unsigned short* __restrict__ W1t) {
  __shared__ float tile[64][65];
  int e = blockIdx.z, h0 = blockIdx.x * 64, d0 = blockIdx.y * 64;
  const float* src = W1 + (size_t)e * N_D * N_H;
  unsigned short* dst = W1t + (size_t)e * N_H * N_D;
  int tx = threadIdx.x & 15, ty = threadIdx.x >> 4;
  for (int s = 0; s < 4; ++s) {
    int d = s * 16 + ty;
    float4 v = *(const float4*)&src[(size_t)(d0 + d) * N_H + h0 + tx * 4];
    tile[d][tx * 4 + 0] = v.x;
    tile[d][tx * 4 + 1] = v.y;
    tile[d][tx * 4 + 2] = v.z;
    tile[d][tx * 4 + 3] = v.w;
  }
  __syncthreads();
  int px = threadIdx.x & 7, py = threadIdx.x >> 3;
  for (int s = 0; s < 2; ++s) {
    int h = s * 32 + py;
    short8 v;
    for (int j = 0; j < 8; ++j)
      v[j] = (short)f2bf(tile[px * 8 + j][h]);
    *(short8*)&dst[(size_t)(h0 + h) * N_D + d0 + px * 8] = v;
  }
}

// ---------------- fused grouped GEMM1 + relu + layer2 ----------------------
// Expert-affine XCD schedule via slot table (p&7 = XCD under round-robin
// dispatch). Depth-2 pipeline, raw asm waitcnt+barrier (vmcnt never drains
// to 0 mid-loop), chunk-major LDS -> conflict-free ds_read_b128.

__global__ __launch_bounds__(256, 4) void k_gemm(
    const unsigned short* __restrict__ Xg, const unsigned short* __restrict__ W1t,
    const float* __restrict__ b1, const float* __restrict__ W2,
    const float* __restrict__ b2, const int* __restrict__ sorted,
    const int* __restrict__ counts, const int* __restrict__ offsets,
    const int* __restrict__ slots, float* __restrict__ out) {
  const int p = blockIdx.x;
  const int sv = slots[(p & 7) * SLOTMAX + (p >> 3)];
  if (sv < 0) return;
  const int e = sv & 255;
  const int m0 = ((sv >> 8) & 255) * MT;
  const int n0 = (sv >> 16) * NT;
  const int off = offsets[e];
  const int cnt_rel = counts[e] - m0;

  __shared__ unsigned short lA[2][MT * BK];  // 2 x 8KB, chunk-major groups
  __shared__ unsigned short lB[2][NT * BK];

  const int tid = threadIdx.x;
  const int wid = tid >> 6, lane = tid & 63;
  const int wm = (wid >> 1) * 64, wn = (wid & 1) * 64;
  const int quad = lane >> 4, lm = lane & 15;

  // staging lane mapping: row = lane&15 (+R0), k-chunk = lane>>4.
  const int R0 = wid * 32 + lm;
  const char* agp = (const char*)Xg + (size_t)(off + m0 + R0) * ROWB + quad * 16;
  const char* bgp = (const char*)W1t + (size_t)e * N_H * ROWB +
                    (size_t)(n0 + R0) * ROWB + quad * 16;
  unsigned short* lap[2] = {&lA[0][(wid * 32) * BK], &lA[1][(wid * 32) * BK]};
  unsigned short* lbp[2] = {&lB[0][(wid * 32) * BK], &lB[1][(wid * 32) * BK]};

#define ISSUE_BATCH(kk, b)                                                       \
  do {                                                                           \
    const char* a_ = agp + (kk)*64;                                              \
    const char* b_ = bgp + (kk)*64;                                              \
    GLD_LDS16(a_, lap[b]);                                                       \
    GLD_LDS16(a_ + 16 * ROWB, lap[b] + 16 * BK);                                 \
    GLD_LDS16(b_, lbp[b]);                                                       \
    GLD_LDS16(b_ + 16 * ROWB, lbp[b] + 16 * BK);                                 \
  } while (0)

  f32x4 acc[4][4] = {};

  ISSUE_BATCH(0, 0);
  ISSUE_BATCH(1, 1);

  // fragment address (chunk-major): elem = ((m>>4)*4 + quad)*128 + lm*8
  const int fa = quad * 128 + lm * 8;

#define GEMM_BODY(kt, cur, DO_ISSUE)                                             \
  do {                                                                           \
    short8 af[4], bfr[4];                                                        \
    for (int i = 0; i < 4; ++i)                                                  \
      af[i] = *(const short8*)&lA[cur][((wm >> 4) + i) * 512 + fa];              \
    for (int j = 0; j < 4; ++j)                                                  \
      bfr[j] = *(const short8*)&lB[cur][((wn >> 4) + j) * 512 + fa];             \
    asm volatile("s_waitcnt lgkmcnt(0)\n\ts_barrier" ::: "memory");              \
    if (DO_ISSUE) ISSUE_BATCH((kt) + 2, cur);                                    \
    for (int i = 0; i < 4; ++i)                                                  \
      for (int j = 0; j < 4; ++j)                                                \
        acc[i][j] = __builtin_amdgcn_mfma_f32_16x16x32_bf16(af[i], bfr[j],       \
                                                            acc[i][j], 0, 0, 0); \
  } while (0)

#pragma unroll
  for (int kt = 0; kt < KT - 1; ++kt) {
    const int cur = kt & 1;
    asm volatile("s_waitcnt vmcnt(4)\n\ts_barrier" ::: "memory");
    GEMM_BODY(kt, cur, kt < KT - 2);
  }
  {
    asm volatile("s_waitcnt vmcnt(0)\n\ts_barrier" ::: "memory");
    GEMM_BODY(KT - 1, (KT - 1) & 1, false);
  }

  // ---- fused epilogue: h = relu(acc + b1), y-partial = h * W2[e] ----
  // C/D layout: col = lane&15 (lm), row = quad*4 + reg
  float y0[4][4], y1[4][4];
  for (int i = 0; i < 4; ++i)
    for (int r = 0; r < 4; ++r) y0[i][r] = y1[i][r] = 0.f;

  for (int j = 0; j < 4; ++j) {
    int col = n0 + wn + j * 16 + lm;
    float bias = b1[e * N_H + col];
    float2 w2 = *(const float2*)&W2[((size_t)e * N_H + col) * N_C];
    for (int i = 0; i < 4; ++i) {
      f32x4 a = acc[i][j];
      for (int r = 0; r < 4; ++r) {
        float h = a[r] + bias;
        h = h > 0.f ? h : 0.f;
        y0[i][r] += h * w2.x;
        y1[i][r] += h * w2.y;
      }
    }
  }
  for (int s = 1; s < 16; s <<= 1) {
    for (int i = 0; i < 4; ++i)
      for (int r = 0; r < 4; ++r) {
        y0[i][r] += __shfl_xor(y0[i][r], s, 64);
        y1[i][r] += __shfl_xor(y1[i][r], s, 64);
      }
  }
  if (lm == 0) {
    const bool add_bias = (n0 == 0) && (wn == 0);
    float bb0 = add_bias ? b2[e * N_C + 0] : 0.f;
    float bb1 = add_bias ? b2[e * N_C + 1] : 0.f;
    for (int i = 0; i < 4; ++i) {
      for (int r = 0; r < 4; ++r) {
        int mrel = wm + i * 16 + quad * 4 + r;
        if (mrel < cnt_rel) {
          int token = sorted[off + m0 + mrel];
          atomicAdd(&out[(size_t)token * N_C + 0], y0[i][r] + bb0);
          atomicAdd(&out[(size_t)token * N_C + 1], y1[i][r] + bb1);
        }
      }
    }
  }
}

// ---------------- launch ----------------

extern "C" void kernel_launch(void* const* d_in, const int* in_sizes, int n_in,
                              void* d_out, int out_size, void* d_ws, size_t ws_size,
                              hipStream_t stream) {
  const float* emb = (const float*)d_in[0];
  const int* cidx = (const int*)d_in[1];
  const float* W1 = (const float*)d_in[2];
  const float* b1 = (const float*)d_in[3];
  const float* W2 = (const float*)d_in[4];
  const float* b2 = (const float*)d_in[5];
  float* out = (float*)d_out;
  const int n = in_sizes[1];

  // ws: 0 counts[32] | 128 offsets[32] | 256 cursor[32] | 1024 slots[8*160]
  //     | 8192 sorted[n] | Xg bf16 | W1t bf16
  char* ws = (char*)d_ws;
  int* counts = (int*)ws;
  int* offsets = (int*)(ws + 128);
  int* cursor = (int*)(ws + 256);
  int* slots = (int*)(ws + 1024);
  int* sorted = (int*)(ws + 8192);
  size_t sorted_bytes = ((size_t)n * 4 + 255) & ~(size_t)255;
  unsigned short* Xg = (unsigned short*)(ws + 8192 + sorted_bytes);
  int pcap = n + MT;  // zero-padded tail rows
  unsigned short* W1t = Xg + (size_t)pcap * N_D;

  hipMemsetAsync(d_ws, 0, 1024, stream);
  hipMemsetAsync(d_out, 0, (size_t)out_size * sizeof(float), stream);
  int nb = (n + 255) / 256;
  k_hist<<<nb, 256, 0, stream>>>(cidx, counts, n);
  k_scan<<<1, 64, 0, stream>>>(counts, offsets, cursor, slots);
  k_scatter<<<nb, 256, 0, stream>>>(cidx, cursor, sorted, n);
  k_gather<<<pcap, 192, 0, stream>>>(emb, sorted, Xg, n);
  k_w1_cvt<<<dim3(N_H / 64, N_D / 64, N_E), 256, 0, stream>>>(W1, W1t);
  k_gemm<<<8 * SLOTMAX, 256, 0, stream>>>(Xg, W1t, b1, W2, b2, sorted, counts,
                                          offsets, slots, out);
}